// Round 14
// baseline (22.680 us; speedup 1.0000x reference)
//
#include <hip/hip_runtime.h>
#include <hip/hip_bf16.h>

#define BATCH 4
#define NB    256
#define NE    (NB*(NB-1))   // 65280

typedef short    short8 __attribute__((ext_vector_type(8)));
typedef float    f32x16 __attribute__((ext_vector_type(16)));

static __device__ __forceinline__ short f2bf(float x) {
    return __builtin_bit_cast(short, __float2bfloat16(x));   // RNE
}
static __device__ __forceinline__ float bf2f(short s) {
    unsigned u = ((unsigned)(unsigned short)s) << 16;
    return __builtin_bit_cast(float, u);
}
static __device__ __forceinline__ f32x16 splat16(float v) {
    f32x16 r;
    #pragma unroll
    for (int e = 0; e < 16; ++e) r[e] = v;
    return r;
}

#define MFMA(C, A, B) C = __builtin_amdgcn_mfma_f32_32x32x16_bf16(A, B, C, 0, 0, 0)

// W1 B-frag from LDS f32 (stride-64 scalar LDS reads, conflict-free)
#define MK_BW(dst, BASE, K0, NT) do {                                          \
    const float* _p = W1l + (BASE) + (16*(K0) + 8*lh) * 64 + l31 + 32*(NT);    \
    short8 _v;                                                                 \
    _v[0]=f2bf(_p[0]);   _v[1]=f2bf(_p[64]);  _v[2]=f2bf(_p[128]);             \
    _v[3]=f2bf(_p[192]); _v[4]=f2bf(_p[256]); _v[5]=f2bf(_p[320]);             \
    _v[6]=f2bf(_p[384]); _v[7]=f2bf(_p[448]);                                  \
    (dst) = _v; } while (0)

// ---------------------------------------------------------------------------
// prep (65 wgs): blk<64 = (i, b, 32-node octant); each wave does ONE GEMM
// block (P/Q x N-tile) -> 4x shorter critical path than R13's 17-wg prep.
// blk==64 = W2 -> bf16 B-fragments.
//   Pbf [i*4+b][hb][n][8] bf16 : P = x·W1[:64]   (A-frag layout)
//   Qg  [i*4+b][n][64]   f32   : x·W1[64:] + b1
//   W2f [2][2][4][64][8] bf16
// ---------------------------------------------------------------------------
__global__ __launch_bounds__(256) void prep_kernel(
    const float* __restrict__ x,   // [B][N][64]
    const float* __restrict__ W1,  // [2][128][64]
    const float* __restrict__ b1,  // [2][64]
    const float* __restrict__ W2,  // [2][64][64]
    short* __restrict__ Pbf,
    float* __restrict__ Qg,
    short* __restrict__ W2f)
{
    const int t    = threadIdx.x;
    const int lane = t & 63;
    const int w    = t >> 6;
    const int l31  = lane & 31;
    const int lh   = lane >> 5;
    const int blk  = blockIdx.x;

    __shared__ __align__(16) float W1l[8192];   // 32 KiB: W1[i] full
    __shared__ __align__(16) short xbf[2048];   // 4 KiB: 32 x-rows bf16, swizzled

    if (blk < 64) {
        const int i   = blk >> 5;
        const int rem = blk & 31;
        const int bp  = rem >> 3;
        const int n0  = (rem & 7) * 32;
        const int ibb = i * 4 + bp;
        const float* xb = x + (size_t)bp * NB * 64;

        #pragma unroll
        for (int q = 0; q < 8; ++q) {              // W1[i] -> LDS, coalesced
            const int e = (q * 256 + t) * 4;
            *(float4*)(W1l + e) = *(const float4*)(W1 + (size_t)i * 8192 + e);
        }
        {                                          // 32 x-rows -> bf16 swizzled
            const int row = t >> 3;                // 0..31
            const int f0  = (t & 7) * 8;
            const float* src = xb + (n0 + row) * 64 + f0;
            float4 v0 = *(const float4*)(src);
            float4 v1 = *(const float4*)(src + 4);
            short8 s = { f2bf(v0.x), f2bf(v0.y), f2bf(v0.z), f2bf(v0.w),
                         f2bf(v1.x), f2bf(v1.y), f2bf(v1.z), f2bf(v1.w) };
            const int sw = (row & 7) << 4;
            *(short8*)((char*)xbf + row * 128 + ((f0 * 2) ^ sw)) = s;
        }
        __syncthreads();

        const int swr = (l31 & 7) << 4;
        const short8 XB0 = *(const short8*)((const char*)xbf + l31*128 + ((16*lh)      ^ swr));
        const short8 XB1 = *(const short8*)((const char*)xbf + l31*128 + ((32 + 16*lh) ^ swr));
        const short8 XB2 = *(const short8*)((const char*)xbf + l31*128 + ((64 + 16*lh) ^ swr));
        const short8 XB3 = *(const short8*)((const char*)xbf + l31*128 + ((96 + 16*lh) ^ swr));

        // wave task: w=0 P/nt0, w=1 P/nt1, w=2 Q/nt0, w=3 Q/nt1
        const int base = (w < 2) ? 0 : 4096;       // sender rows / receiver rows
        const int nt   = w & 1;
        short8 B0, B1, B2, B3;
        MK_BW(B0, base, 0, nt); MK_BW(B1, base, 1, nt);
        MK_BW(B2, base, 2, nt); MK_BW(B3, base, 3, nt);
        f32x16 c = splat16(0.f);
        MFMA(c, XB0, B0); MFMA(c, XB1, B1); MFMA(c, XB2, B2); MFMA(c, XB3, B3);

        if (w < 2) {
            const int hh = l31 + 32 * nt;
            #pragma unroll
            for (int rg = 0; rg < 16; ++rg) {
                const int nn = n0 + (rg & 3) + 8 * (rg >> 2) + 4 * lh;
                Pbf[(size_t)ibb * 16384 + (hh >> 3) * 2048 + nn * 8 + (hh & 7)] = f2bf(c[rg]);
            }
        } else {
            const float b1v = b1[i * 64 + 32 * nt + l31];
            #pragma unroll
            for (int rg = 0; rg < 16; ++rg) {
                const int nn = n0 + (rg & 3) + 8 * (rg >> 2) + 4 * lh;
                Qg[(size_t)ibb * 16384 + nn * 64 + 32 * nt + l31] = c[rg] + b1v;
            }
        }
    } else {
        // W2 -> fragments, source-coalesced reads, small scatter writes
        #pragma unroll
        for (int q = 0; q < 32; ++q) {
            const int e = q * 256 + t;             // == i*4096 + k*64 + n
            const int i = e >> 12, k = (e >> 6) & 63, n = e & 63;
            const float v = W2[e];
            const int k0 = k >> 4, j = k & 7, hm = (k >> 3) & 1;
            const int nt = n >> 5;
            W2f[(((i*2 + nt)*4 + k0)*64 + hm*32 + (n & 31))*8 + j] = f2bf(v);
        }
    }
}

// ---------------------------------------------------------------------------
// main: byte-identical to R13 (22.5 µs, twice-reproduced) — one wg per
// (b, receiver r); 4 waves; sequential h-halves; 4-frag P pipeline.
// ---------------------------------------------------------------------------

// A2 frag: relu(bf2f(P) + qrow) -> bf16, k-elems h = 16*K0+8*lh+j
#define MK_A2(dst, PV, I, K0) do {                                             \
    float4 _q0 = *(const float4*)(&qrow[I][16*(K0) + 8*lh]);                   \
    float4 _q1 = *(const float4*)(&qrow[I][16*(K0) + 8*lh + 4]);               \
    short8 _v;                                                                 \
    _v[0] = f2bf(fmaxf(bf2f((PV)[0]) + _q0.x, 0.f));                           \
    _v[1] = f2bf(fmaxf(bf2f((PV)[1]) + _q0.y, 0.f));                           \
    _v[2] = f2bf(fmaxf(bf2f((PV)[2]) + _q0.z, 0.f));                           \
    _v[3] = f2bf(fmaxf(bf2f((PV)[3]) + _q0.w, 0.f));                           \
    _v[4] = f2bf(fmaxf(bf2f((PV)[4]) + _q1.x, 0.f));                           \
    _v[5] = f2bf(fmaxf(bf2f((PV)[5]) + _q1.y, 0.f));                           \
    _v[6] = f2bf(fmaxf(bf2f((PV)[6]) + _q1.z, 0.f));                           \
    _v[7] = f2bf(fmaxf(bf2f((PV)[7]) + _q1.w, 0.f));                           \
    (dst) = _v; } while (0)

// epilogue quad into ONE psum (h-halves processed sequentially)
#define EPI_Q(C, PS, I, ET, QD) do {                                           \
    float4 _rq = *(const float4*)(&rt2[I][64*w + 32*(ET) + 8*(QD) + 4*lh]);    \
    PS += fmaxf((C)[4*(QD)],   0.f) * _rq.x;                                   \
    PS += fmaxf((C)[4*(QD)+1], 0.f) * _rq.y;                                   \
    PS += fmaxf((C)[4*(QD)+2], 0.f) * _rq.z;                                   \
    PS += fmaxf((C)[4*(QD)+3], 0.f) * _rq.w; } while (0)

#define TILE2(I, ET, PA, PB, PC, PD, BVA, BVB) do {                            \
    short8 _a0, _a1, _a2, _a3;                                                 \
    MK_A2(_a0, PA, I, 0); MK_A2(_a1, PB, I, 1);                                \
    MK_A2(_a2, PC, I, 2); MK_A2(_a3, PD, I, 3);                                \
    {                                                                          \
        f32x16 _c = splat16(BVA);                                              \
        MFMA(_c, _a0, *(const short8*)(W2l + (((I)*8 + 0)*64 + lane)*8));      \
        MFMA(_c, _a1, *(const short8*)(W2l + (((I)*8 + 1)*64 + lane)*8));      \
        MFMA(_c, _a2, *(const short8*)(W2l + (((I)*8 + 2)*64 + lane)*8));      \
        MFMA(_c, _a3, *(const short8*)(W2l + (((I)*8 + 3)*64 + lane)*8));      \
        EPI_Q(_c, psum0, I, ET, 0); EPI_Q(_c, psum0, I, ET, 1);                \
        EPI_Q(_c, psum0, I, ET, 2); EPI_Q(_c, psum0, I, ET, 3);                \
    }                                                                          \
    {                                                                          \
        f32x16 _c = splat16(BVB);                                              \
        MFMA(_c, _a0, *(const short8*)(W2l + (((I)*8 + 4)*64 + lane)*8));      \
        MFMA(_c, _a1, *(const short8*)(W2l + (((I)*8 + 5)*64 + lane)*8));      \
        MFMA(_c, _a2, *(const short8*)(W2l + (((I)*8 + 6)*64 + lane)*8));      \
        MFMA(_c, _a3, *(const short8*)(W2l + (((I)*8 + 7)*64 + lane)*8));      \
        EPI_Q(_c, psum1, I, ET, 0); EPI_Q(_c, psum1, I, ET, 1);                \
        EPI_Q(_c, psum1, I, ET, 2); EPI_Q(_c, psum1, I, ET, 3);                \
    } } while (0)

#define LD_P(I, K0, S) \
    (*(const short8*)(PbfG + ((size_t)((I)*4+b)*8 + 2*(K0)+lh)*2048 + (size_t)(S)*8))

__global__ __launch_bounds__(256, 3) void main_kernel(
    const float* __restrict__ x,
    const float* __restrict__ rel_type, // [B][E][2]
    const float* __restrict__ b2,       // [2][64]
    const float* __restrict__ Wo1,      // [128][64]
    const float* __restrict__ bo1,
    const float* __restrict__ Wo2,      // [64][64]
    const float* __restrict__ bo2,
    const short* __restrict__ PbfG,
    const float* __restrict__ Qg,
    const short* __restrict__ W2fG,
    float* __restrict__ out)
{
    const int b    = blockIdx.x >> 8;
    const int r    = blockIdx.x & 255;
    const int t    = threadIdx.x;
    const int lane = t & 63;
    const int w    = t >> 6;
    const int l31  = lane & 31;
    const int lh   = lane >> 5;

    __shared__ __align__(16) short W2l[8192];      // 16 KiB
    __shared__ __align__(16) float rt2[2][256];
    __shared__ __align__(16) float qrow[2][64];
    __shared__ __align__(16) float red[4][64];
    __shared__ __align__(16) float xl[64];
    __shared__ __align__(16) float aggl[64];
    __shared__ __align__(16) float predl[64];

    const float* xb = x + (size_t)b * NB * 64;

    // ---- staging ----
    if (t < 255) {
        const float2 pv = *(const float2*)(rel_type + ((size_t)b * NE + (size_t)r * 255 + t) * 2);
        rt2[0][t] = pv.x;
        rt2[1][t] = pv.y;
    } else {
        rt2[0][255] = 0.f; rt2[1][255] = 0.f;      // pad edge contributes 0
    }
    #pragma unroll
    for (int q = 0; q < 4; ++q) {                  // W2 frags -> LDS (b128 copy)
        const int e = (q * 256 + t) * 8;
        *(short8*)(W2l + e) = *(const short8*)(W2fG + e);
    }
    if (t < 128) {
        const int i = t >> 6, h = t & 63;
        qrow[i][h] = Qg[(size_t)(i * 4 + b) * 16384 + r * 64 + h];
    }
    if (t >= 192) xl[t - 192] = xb[r * 64 + (t - 192)];

    // edge rows for this wave's two M-tiles
    const int kap0 = 64 * w + l31;
    const int kap1 = kap0 + 32;
    int s0 = (kap0 < r) ? kap0 : kap0 + 1; if (s0 > 255) s0 = 255;  // pad row
    int s1 = (kap1 < r) ? kap1 : kap1 + 1; if (s1 > 255) s1 = 255;

    // first P set (type 0, s0): 4 frags = 16 VGPR
    short8 P00 = LD_P(0,0,s0), P01 = LD_P(0,1,s0), P02 = LD_P(0,2,s0), P03 = LD_P(0,3,s0);

    const float bv00 = b2[l31],      bv01 = b2[32 + l31];
    const float bv10 = b2[64 + l31], bv11 = b2[96 + l31];

    __syncthreads();

    float psum0 = 0.f, psum1 = 0.f;   // per-lane agg partials, h = l31 / l31+32

    // issue next set before compute (T14): latency hides under MFMA
    short8 P10 = LD_P(0,0,s1), P11 = LD_P(0,1,s1), P12 = LD_P(0,2,s1), P13 = LD_P(0,3,s1);
    TILE2(0, 0, P00, P01, P02, P03, bv00, bv01);

    P00 = LD_P(1,0,s0); P01 = LD_P(1,1,s0); P02 = LD_P(1,2,s0); P03 = LD_P(1,3,s0);
    TILE2(0, 1, P10, P11, P12, P13, bv00, bv01);

    P10 = LD_P(1,0,s1); P11 = LD_P(1,1,s1); P12 = LD_P(1,2,s1); P13 = LD_P(1,3,s1);
    TILE2(1, 0, P00, P01, P02, P03, bv10, bv11);

    TILE2(1, 1, P10, P11, P12, P13, bv10, bv11);

    // ---- reduce: lane-halves, then waves ----
    psum0 += __shfl_xor(psum0, 32, 64);
    psum1 += __shfl_xor(psum1, 32, 64);
    if (lh == 0) {
        red[w][l31]      = psum0;
        red[w][l31 + 32] = psum1;
    }
    __syncthreads();
    if (t < 64) aggl[t] = red[0][t] + red[1][t] + red[2][t] + red[3][t];
    __syncthreads();

    // ---- output MLP layer 1: aug(128) @ Wo1(128x64) ----
    {
        const float* src = (w < 2) ? (xl + w * 32) : (aggl + (w - 2) * 32);
        const float* Wp  = Wo1 + (w * 32) * 64 + lane;
        float s = 0.f;
        #pragma unroll
        for (int jj = 0; jj < 32; ++jj) s = fmaf(src[jj], Wp[jj * 64], s);
        red[w][lane] = s;
    }
    __syncthreads();
    if (t < 64)
        predl[t] = fmaxf(red[0][t] + red[1][t] + red[2][t] + red[3][t] + bo1[t], 0.f);
    __syncthreads();

    // ---- output MLP layer 2 + residual ----
    {
        const float* Wp = Wo2 + (w * 16) * 64 + lane;
        float s = 0.f;
        #pragma unroll
        for (int jj = 0; jj < 16; ++jj) s = fmaf(predl[w * 16 + jj], Wp[jj * 64], s);
        red[w][lane] = s;
    }
    __syncthreads();
    if (t < 64)
        out[((size_t)b * NB + r) * 64 + t] =
            xl[t] + fmaxf(red[0][t] + red[1][t] + red[2][t] + red[3][t] + bo2[t], 0.f);
}

// ---------------------------------------------------------------------------
extern "C" void kernel_launch(void* const* d_in, const int* in_sizes, int n_in,
                              void* d_out, int out_size, void* d_ws, size_t ws_size,
                              hipStream_t stream) {
    (void)in_sizes; (void)n_in; (void)out_size; (void)ws_size;

    const float* x    = (const float*)d_in[0];
    const float* rt   = (const float*)d_in[1];
    // d_in[2] = rel_rec, d_in[3] = rel_send: dense all-pairs one-hot, unused
    const float* W1   = (const float*)d_in[4];
    const float* b1   = (const float*)d_in[5];
    const float* W2   = (const float*)d_in[6];
    const float* b2   = (const float*)d_in[7];
    const float* Wo1  = (const float*)d_in[8];
    const float* bo1  = (const float*)d_in[9];
    const float* Wo2  = (const float*)d_in[10];
    const float* bo2  = (const float*)d_in[11];
    float* out = (float*)d_out;

    char* ws = (char*)d_ws;
    short* Pbf = (short*)ws;                 // 8*16384*2B  = 256 KiB
    float* Qg  = (float*)(ws + 262144);      // 8*16384*4B  = 512 KiB
    short* W2f = (short*)(ws + 786432);      // 16 KiB

    prep_kernel<<<65, 256, 0, stream>>>(x, W1, b1, W2, Pbf, Qg, W2f);
    main_kernel<<<BATCH * NB, 256, 0, stream>>>(x, rt, b2, Wo1, bo1, Wo2, bo2,
                                                Pbf, Qg, W2f, out);
}